// Round 3
// baseline (124.994 us; speedup 1.0000x reference)
//
#include <hip/hip_runtime.h>
#include <math.h>

#define NBOX 98            // 7*7*2
#define ROWLEN 1470        // 7*7*30
#define NMS_T 0.7f
#define SCORE_T 0.05f

__device__ __forceinline__ float sigm(float v) {
    return 1.0f / (1.0f + expf(-v));
}

__global__ __launch_bounds__(128) void yolo_post(const float* __restrict__ x,
                                                 float* __restrict__ out,
                                                 int batch) {
    const int b    = blockIdx.x;
    const int tid  = threadIdx.x;
    const int wid  = tid >> 6;
    const int lane = tid & 63;

    // row[1470] (5880B) is dead after decode; post-decode arrays alias it.
    __shared__ __align__(16) char ubuf[ROWLEN * 4];
    __shared__ unsigned long long m0h[2 * NBOX], m1h[2 * NBOX];  // per-half partial masks
    __shared__ unsigned long long aliveW[2];
    __shared__ int sCnt[2];

    float*  row    = reinterpret_cast<float*>(ubuf);
    float4* sbox   = reinterpret_cast<float4*>(ubuf);          // [98] 0..1568
    float*  cscore = reinterpret_cast<float*>(ubuf + 1568);    // [98]
    float*  sarea  = reinterpret_cast<float*>(ubuf + 1960);    // [98]
    float*  ssc    = reinterpret_cast<float*>(ubuf + 2352);    // [98]
    float*  slabf  = reinterpret_cast<float*>(ubuf + 2744);    // [98] label as float

    // ---- stage input row (float2, coalesced) ----
    const float2* xr2 = reinterpret_cast<const float2*>(x + (size_t)b * ROWLEN);
    float2* row2 = reinterpret_cast<float2*>(row);
    #pragma unroll
    for (int i = 0; i < 6; ++i) {
        const int idx = tid + i * 128;
        if (idx < ROWLEN / 2) row2[idx] = xr2[idx];
    }
    __syncthreads();

    // ---- decode box tid into registers ----
    float4 box = make_float4(0.f, 0.f, 0.f, 0.f);
    float  mx  = 0.f, mlf = 0.f;
    bool   valid = false;
    if (tid < NBOX) {
        const int k  = tid >> 1;
        const int a  = tid & 1;
        const int ci = k / 7;
        const int cj = k - ci * 7;
        const float* p = row + k * 30 + a * 5;
        const float bx = sigm(p[0]) + (float)cj * 64.0f;
        const float by = sigm(p[1]) + (float)ci * 64.0f;
        const float bw = sigm(p[2]);
        const float bh = sigm(p[3]);
        valid = (p[4] >= 0.0f);           // sigmoid(o) >= 0.5  <=>  o >= 0

        const float* cc = row + k * 30 + 10;
        mx = cc[0]; int ml = 0;
        #pragma unroll
        for (int t = 1; t < 20; ++t) {
            const float v = cc[t];
            if (v > mx) { mx = v; ml = t; }
        }
        mlf = (float)ml;
        box.x = fminf(fmaxf(bx, 0.f), 1.f);
        box.y = fminf(fmaxf(by, 0.f), 1.f);
        box.z = fminf(fmaxf(bx + bw, 0.f), 1.f);
        box.w = fminf(fmaxf(by + bh, 0.f), 1.f);
    }

    // ---- compact valid boxes (order-preserving) ----
    const unsigned long long bal = __ballot(valid);
    if (lane == 0) sCnt[wid] = (int)__popcll(bal);
    __syncthreads();                       // also: all row reads complete before aliased writes
    const int V = sCnt[0] + sCnt[1];
    const int c = (int)__popcll(bal & ((1ull << lane) - 1ull)) + (wid ? sCnt[0] : 0);
    if (valid) cscore[c] = mx;
    __syncthreads();

    // ---- stable descending rank among valid + scatter to sorted arrays ----
    if (valid) {
        int rank = 0;
        for (int j = 0; j < V; ++j) {
            const float kj = cscore[j];    // broadcast read
            rank += (kj > mx) || ((kj == mx) && (j < c));
        }
        sbox[rank]  = box;
        sarea[rank] = (box.z - box.x) * (box.w - box.y);
        ssc[rank]   = mx;
        slabf[rank] = mlf;
    }
    __syncthreads();

    // ---- suppression masks, j-range split across the two waves ----
    const int Vh  = (V + 1) >> 1;
    const int jlo = wid ? Vh : 0;
    const int jhi = wid ? V  : Vh;

    auto iou_row = [&](int i) {
        const float4 bi = sbox[i];
        const float  ai = sarea[i];
        unsigned long long mm0 = 0ull, mm1 = 0ull;
        const int e0 = (jhi < 64) ? jhi : 64;
        for (int j = jlo; j < e0; ++j) {
            const float4 bj = sbox[j];
            const float w = fmaxf(fminf(bi.z, bj.z) - fmaxf(bi.x, bj.x), 0.f);
            const float h = fmaxf(fminf(bi.w, bj.w) - fmaxf(bi.y, bj.y), 0.f);
            const float inter = w * h;
            const float uni = (ai + sarea[j]) - inter;   // ref op order
            if (uni > 0.f && inter > NMS_T * uni) mm0 |= (1ull << j);
        }
        const int s1 = (jlo > 64) ? jlo : 64;
        for (int j = s1; j < jhi; ++j) {
            const float4 bj = sbox[j];
            const float w = fmaxf(fminf(bi.z, bj.z) - fmaxf(bi.x, bj.x), 0.f);
            const float h = fmaxf(fminf(bi.w, bj.w) - fmaxf(bi.y, bj.y), 0.f);
            const float inter = w * h;
            const float uni = (ai + sarea[j]) - inter;
            if (uni > 0.f && inter > NMS_T * uni) mm1 |= (1ull << (j - 64));
        }
        // keep only bits j > i
        if (i < 64) {
            mm0 &= ~((2ull << i) - 1ull);   // i==63: (2ull<<63)==0 -> mask clears all of mm0
        } else {
            mm0 = 0ull;
            mm1 &= ~((2ull << (i - 64)) - 1ull);
        }
        m0h[wid * NBOX + i] = mm0;
        m1h[wid * NBOX + i] = mm1;
    };

    if (lane < V) iou_row(lane);
    if (V > 64) {
        const int i1 = 64 + lane;
        if (i1 < V) iou_row(i1);
    }
    __syncthreads();

    // ---- greedy sweep (thread 0, branchless, loads pipeline) ----
    if (tid == 0) {
        unsigned long long a0 = (V >= 64) ? ~0ull : ((1ull << V) - 1ull);
        unsigned long long a1 = (V > 64) ? ((1ull << (V - 64)) - 1ull) : 0ull;
        const int e = (V < 64) ? V : 64;
        for (int i = 0; i < e; ++i) {
            const unsigned long long take = 0ull - ((a0 >> i) & 1ull);
            a0 &= ~((m0h[i] | m0h[NBOX + i]) & take);
            a1 &= ~((m1h[i] | m1h[NBOX + i]) & take);
        }
        for (int i = 64; i < V; ++i) {
            const unsigned long long take = 0ull - ((a1 >> (i - 64)) & 1ull);
            a1 &= ~((m1h[i] | m1h[NBOX + i]) & take);
        }
        aliveW[0] = a0; aliveW[1] = a1;
    }
    __syncthreads();

    // ---- outputs: boxes [b,98,4] | scores [b,98] | labels [b,98] | keep [b,98] ----
    if (tid < NBOX) {
        float4 bo = make_float4(0.f, 0.f, 0.f, 0.f);
        float so = 0.f, lo = 0.f, ko = 0.f;
        if (tid < V) {
            const bool al = (tid < 64) ? ((aliveW[0] >> tid) & 1ull)
                                       : ((aliveW[1] >> (tid - 64)) & 1ull);
            const float s = ssc[tid];
            if (al && s >= SCORE_T) {
                bo = sbox[tid]; so = s; lo = slabf[tid]; ko = 1.0f;
            }
        }
        *reinterpret_cast<float4*>(out + (size_t)b * (NBOX * 4) + (size_t)tid * 4) = bo;
        const size_t base1 = (size_t)batch * (NBOX * 4);
        const size_t bn    = (size_t)batch * NBOX;
        out[base1 +          (size_t)b * NBOX + tid] = so;
        out[base1 + bn +     (size_t)b * NBOX + tid] = lo;
        out[base1 + 2 * bn + (size_t)b * NBOX + tid] = ko;
    }
}

extern "C" void kernel_launch(void* const* d_in, const int* in_sizes, int n_in,
                              void* d_out, int out_size, void* d_ws, size_t ws_size,
                              hipStream_t stream) {
    const float* x = (const float*)d_in[0];
    float* out = (float*)d_out;
    const int batch = in_sizes[0] / ROWLEN;   // 8192
    yolo_post<<<batch, 128, 0, stream>>>(x, out, batch);
}

// Round 4
// 100.568 us; speedup vs baseline: 1.2429x; 1.2429x over previous
//
#include <hip/hip_runtime.h>
#include <math.h>

#define NBOX 98            // 7*7*2
#define ROWLEN 1470        // floats per image
#define ROWPAD 1472        // per-wave LDS region, 8B-multiple
#define NMS_T 0.7f
#define SCORE_T 0.05f

__device__ __forceinline__ float sigm(float v) {
    return 1.0f / (1.0f + expf(-v));
}

__device__ __forceinline__ float rdlane_f(float v, int l) {
    return __int_as_float(__builtin_amdgcn_readlane(__float_as_int(v), l));
}

// One wave per image. Cross-lane comms via ballot/readlane only; LDS used
// solely to stage the 1470-float row (coalesced in, per-cell reads out).
//
// Structural fact (holds for ANY input): after decode, every box except the
// two anchors of cell (0,0) has x1==x2==1 (cj>=1) or y1==y2==1 (ci>=1), i.e.
// zero width/height -> inter==0 -> IoU==0 with everything. So greedy NMS can
// only ever suppress box index 1 (by box 0; same cell => same score => box 0
// sorts first and is never suppressible). NMS == one IoU check.
__global__ __launch_bounds__(256) void yolo_post(const float* __restrict__ x,
                                                 float* __restrict__ out,
                                                 int batch) {
    const int wid  = threadIdx.x >> 6;          // wave within block 0..3
    const int lane = threadIdx.x & 63;
    const int b    = blockIdx.x * 4 + wid;      // image index

    __shared__ __align__(16) float srow[4][ROWPAD];
    float* row = srow[wid];

    // ---- stage row: coalesced float2 (row base 5880B = 8B aligned) ----
    if (b < batch) {
        const float2* src = reinterpret_cast<const float2*>(x + (size_t)b * ROWLEN);
        float2* dst = reinterpret_cast<float2*>(row);
        #pragma unroll
        for (int r = 0; r < 12; ++r) {
            const int i = lane + r * 64;
            if (i < ROWLEN / 2) dst[i] = src[i];
        }
    }
    __syncthreads();
    if (b >= batch) return;

    // ---- decode: lane = cell (lanes 0..48), both anchors ----
    const int  cell   = lane;
    const bool active = (cell < 49);

    float  s = 0.0f, lab = 0.0f;
    int    vbits = 0;
    float4 B0 = make_float4(0.f, 0.f, 0.f, 0.f);
    float4 B1 = make_float4(0.f, 0.f, 0.f, 0.f);

    if (active) {
        const float* c = row + cell * 30;
        // shared class argmax (first occurrence)
        float mx = c[10]; int ml = 0;
        #pragma unroll
        for (int t = 1; t < 20; ++t) {
            const float v = c[10 + t];
            if (v > mx) { mx = v; ml = t; }
        }
        s = mx; lab = (float)ml;

        const int ci = cell / 7;
        const int cj = cell - ci * 7;
        const float fx = (float)cj * 64.0f;
        const float fy = (float)ci * 64.0f;

        {   // anchor 0: c[0..4]
            const float bx = sigm(c[0]) + fx;
            const float by = sigm(c[1]) + fy;
            const float bw = sigm(c[2]);
            const float bh = sigm(c[3]);
            B0.x = fminf(fmaxf(bx, 0.f), 1.f);
            B0.y = fminf(fmaxf(by, 0.f), 1.f);
            B0.z = fminf(fmaxf(bx + bw, 0.f), 1.f);
            B0.w = fminf(fmaxf(by + bh, 0.f), 1.f);
            if (c[4] >= 0.0f) vbits |= 1;        // sigmoid(o)>=0.5 <=> o>=0
        }
        {   // anchor 1: c[5..9]
            const float bx = sigm(c[5]) + fx;
            const float by = sigm(c[6]) + fy;
            const float bw = sigm(c[7]);
            const float bh = sigm(c[8]);
            B1.x = fminf(fmaxf(bx, 0.f), 1.f);
            B1.y = fminf(fmaxf(by, 0.f), 1.f);
            B1.z = fminf(fmaxf(bx + bw, 0.f), 1.f);
            B1.w = fminf(fmaxf(by + bh, 0.f), 1.f);
            if (c[9] >= 0.0f) vbits |= 2;
        }
    }

    const bool v0 = (vbits & 1) != 0;
    const bool v1 = (vbits & 2) != 0;

    // ---- validity ballots ----
    const unsigned long long V0m = __ballot(v0);
    const unsigned long long V1m = __ballot(v1);
    const int V = (int)__popcll(V0m) + (int)__popcll(V1m);

    // ---- the single possible NMS suppression: box1 by box0 ----
    bool kill_local = false;
    if (cell == 0 && (vbits & 3) == 3) {
        const float a0 = (B0.z - B0.x) * (B0.w - B0.y);
        const float a1 = (B1.z - B1.x) * (B1.w - B1.y);
        const float w  = fmaxf(fminf(B0.z, B1.z) - fmaxf(B0.x, B1.x), 0.f);
        const float h  = fmaxf(fminf(B0.w, B1.w) - fmaxf(B0.y, B1.y), 0.f);
        const float inter = w * h;
        const float uni   = a0 + a1 - inter;               // ref op order
        const float iou   = (uni > 0.f) ? (inter / uni) : 0.f;  // exact ref form
        kill_local = (iou > NMS_T);
    }
    const bool kill1 = (__ballot(kill_local) != 0ull);

    // ---- rank among valid: (score desc, index asc), via readlane loop ----
    // rcom = # valid boxes strictly before box 2*cell in sort order
    int rcom = 0;
    #pragma unroll 7
    for (int j = 0; j < 49; ++j) {
        const float sj  = rdlane_f(s, j);
        const int   vbj = __builtin_amdgcn_readlane(vbits, j);
        const int   cnt = (vbj & 1) + ((vbj >> 1) & 1);
        const bool  pre = (sj > s) || ((sj == s) && (j < cell));
        rcom += pre ? cnt : 0;
    }

    // prefix of valid boxes among boxes with index < 2*cell
    const unsigned long long below = (1ull << cell) - 1ull;
    const int prefv = (int)__popcll(V0m & below) + (int)__popcll(V1m & below);

    const int r0 = v0 ? rcom
                      : (V + 2 * cell - prefv);
    const int r1 = v1 ? (rcom + (v0 ? 1 : 0))
                      : (V + 2 * cell + 1 - prefv - (v0 ? 1 : 0));

    // ---- keep flags ----
    const bool k0 = v0 && (s >= SCORE_T);
    const bool k1 = v1 && (s >= SCORE_T) && !(kill1 && cell == 0);

    // ---- scatter outputs: boxes [b,98,4] | scores | labels | keep ----
    if (active) {
        float4* boxes = reinterpret_cast<float4*>(out + (size_t)b * (NBOX * 4));
        const size_t base1 = (size_t)batch * (NBOX * 4);
        const size_t bn    = (size_t)batch * NBOX;
        float* scores = out + base1 +          (size_t)b * NBOX;
        float* labels = out + base1 + bn +     (size_t)b * NBOX;
        float* keepm  = out + base1 + 2 * bn + (size_t)b * NBOX;

        const float4 z = make_float4(0.f, 0.f, 0.f, 0.f);
        boxes[r0]  = k0 ? B0 : z;
        boxes[r1]  = k1 ? B1 : z;
        scores[r0] = k0 ? s : 0.f;
        scores[r1] = k1 ? s : 0.f;
        labels[r0] = k0 ? lab : 0.f;
        labels[r1] = k1 ? lab : 0.f;
        keepm[r0]  = k0 ? 1.f : 0.f;
        keepm[r1]  = k1 ? 1.f : 0.f;
    }
}

extern "C" void kernel_launch(void* const* d_in, const int* in_sizes, int n_in,
                              void* d_out, int out_size, void* d_ws, size_t ws_size,
                              hipStream_t stream) {
    const float* x = (const float*)d_in[0];
    float* out = (float*)d_out;
    const int batch = in_sizes[0] / ROWLEN;   // 8192
    const int grid  = (batch + 3) / 4;        // 4 images (waves) per block
    yolo_post<<<grid, 256, 0, stream>>>(x, out, batch);
}

// Round 5
// 98.753 us; speedup vs baseline: 1.2657x; 1.0184x over previous
//
#include <hip/hip_runtime.h>
#include <math.h>

#define NBOX 98            // 7*7*2
#define ROWLEN 1470        // floats per image
#define NMS_T 0.7f
#define SCORE_T 0.05f

// precise sigmoid — bit-matches the reference path (used only in the rare
// IoU-boundary recompute)
__device__ __forceinline__ float psigm(float v) {
    return 1.0f / (1.0f + expf(-v));
}
// fast sigmoid: native exp + v_rcp_f32 (~4 instr, ~1e-7 rel err). Box coords
// only; every comparison/gate in the pipeline uses raw inputs.
__device__ __forceinline__ float fsigm(float v) {
    return __builtin_amdgcn_rcpf(1.0f + __expf(-v));
}

// async global->LDS, 16B per lane; LDS dest = wave-uniform base + lane*16
__device__ __forceinline__ void gl_lds16(const float4* g, float4* l) {
    __builtin_amdgcn_global_load_lds((const __attribute__((address_space(1))) void*)g,
                                     (__attribute__((address_space(3))) void*)l,
                                     16, 0, 0);
}

// One wave per image, 2 images per 128-thread block.
// Structural fact (any input): after decode+clamp, every box except the two
// anchors of cell (0,0) is degenerate (x1==x2==1 for cj>=1, y1==y2==1 for
// ci>=1) -> IoU==0 with everything -> greedy NMS reduces to one IoU check
// (box0 vs box1 of cell 0). Sort = stable rank by (score desc, index asc),
// computed with a packed 64-bit key and a fully-unrolled readlane loop.
__global__ __launch_bounds__(128) void yolo_post(const float* __restrict__ x,
                                                 float* __restrict__ out,
                                                 int batch) {
    const int wid  = threadIdx.x >> 6;          // wave in block: 0..1
    const int lane = threadIdx.x & 63;
    const int b    = blockIdx.x * 2 + wid;      // image index

    // 2 images staged contiguously: 2940 floats = 735 float4 (block base
    // blockIdx*11760B is 16B-aligned for every blockIdx)
    __shared__ __align__(16) float srow[2 * ROWLEN + 4];

    // ---- stage via global_load_lds (width 16), block-cooperative ----
    {
        const float4* gsrc = reinterpret_cast<const float4*>(
            x + (size_t)blockIdx.x * (2 * ROWLEN));
        float4* lrow = reinterpret_cast<float4*>(srow);
        const size_t maxq = ((size_t)batch * ROWLEN) >> 2;           // total float4 in x
        const size_t qbase = (size_t)blockIdx.x * ((2 * ROWLEN) / 4);
        #pragma unroll
        for (int r = 0; r < 6; ++r) {
            const int idx = r * 128 + threadIdx.x;                   // 0..767
            if (idx < 735 && qbase + (size_t)idx < maxq) {
                // LDS base must be wave-uniform: slot r*128 + wid*64
                gl_lds16(gsrc + idx, lrow + (r * 128 + wid * 64));
            }
        }
    }
    __syncthreads();
    if (b >= batch) return;

    const float* row = srow + wid * ROWLEN;

    // ---- decode: lane = cell (0..48) ----
    const int  cell   = lane;
    const bool active = (cell < 49);

    float  s = 0.0f, lab = 0.0f;
    int    vbits = 0;
    float4 B0 = make_float4(1.f, 1.f, 1.f, 1.f);
    float4 B1 = make_float4(1.f, 1.f, 1.f, 1.f);

    if (active) {
        const float* c = row + cell * 30;
        // shared class argmax (first occurrence), raw floats
        float mx = c[10]; int ml = 0;
        #pragma unroll
        for (int t = 1; t < 20; ++t) {
            const float v = c[10 + t];
            if (v > mx) { mx = v; ml = t; }
        }
        s = mx; lab = (float)ml;

        const int ci = cell / 7;
        const int cj = cell - ci * 7;

        // validity from raw sign: sigmoid(o)>=0.5 <=> o>=0
        if (c[4] >= 0.0f) vbits |= 1;
        if (c[9] >= 0.0f) vbits |= 2;

        // fast sigmoids; exact-1.0 override for cj>=1 / ci>=1 (clamp makes the
        // true value exactly 1 there, independent of the logits)
        const float sx0 = fsigm(c[0]), sy0 = fsigm(c[1]);
        const float sw0 = fsigm(c[2]), sh0 = fsigm(c[3]);
        const float sx1 = fsigm(c[5]), sy1 = fsigm(c[6]);
        const float sw1 = fsigm(c[7]), sh1 = fsigm(c[8]);

        if (cj == 0) {
            B0.x = fminf(fmaxf(sx0, 0.f), 1.f);
            B0.z = fminf(fmaxf(sx0 + sw0, 0.f), 1.f);
            B1.x = fminf(fmaxf(sx1, 0.f), 1.f);
            B1.z = fminf(fmaxf(sx1 + sw1, 0.f), 1.f);
        }
        if (ci == 0) {
            B0.y = fminf(fmaxf(sy0, 0.f), 1.f);
            B0.w = fminf(fmaxf(sy0 + sh0, 0.f), 1.f);
            B1.y = fminf(fmaxf(sy1, 0.f), 1.f);
            B1.w = fminf(fmaxf(sy1 + sh1, 0.f), 1.f);
        }
    }

    const bool v0 = (vbits & 1) != 0;
    const bool v1 = (vbits & 2) != 0;
    const int  cnt = (vbits & 1) + (vbits >> 1);

    // ---- validity ballots ----
    const unsigned long long V0m = __ballot(v0);
    const unsigned long long V1m = __ballot(v1);
    const int V = (int)__popcll(V0m) + (int)__popcll(V1m);

    // ---- the single possible suppression: box1 by box0 (cell 0) ----
    bool kill_local = false;
    if (cell == 0 && (vbits & 3) == 3) {
        const float a0 = (B0.z - B0.x) * (B0.w - B0.y);
        const float a1 = (B1.z - B1.x) * (B1.w - B1.y);
        const float w  = fmaxf(fminf(B0.z, B1.z) - fmaxf(B0.x, B1.x), 0.f);
        const float h  = fmaxf(fminf(B0.w, B1.w) - fmaxf(B0.y, B1.y), 0.f);
        const float inter = w * h;
        const float uni   = a0 + a1 - inter;          // > 0 always (areas > 0)
        const float delta = inter - NMS_T * uni;
        if (fabsf(delta) < 1e-4f * uni) {
            // rare (~1e-4): fast-sigmoid error could flip the decision ->
            // recompute this one pair with the ref-exact path
            const float px0 = psigm(row[0]), py0 = psigm(row[1]);
            const float pw0 = psigm(row[2]), ph0 = psigm(row[3]);
            const float px1 = psigm(row[5]), py1 = psigm(row[6]);
            const float pw1 = psigm(row[7]), ph1 = psigm(row[8]);
            const float X0 = fminf(fmaxf(px0, 0.f), 1.f), Y0 = fminf(fmaxf(py0, 0.f), 1.f);
            const float Z0 = fminf(fmaxf(px0 + pw0, 0.f), 1.f), W0 = fminf(fmaxf(py0 + ph0, 0.f), 1.f);
            const float X1 = fminf(fmaxf(px1, 0.f), 1.f), Y1 = fminf(fmaxf(py1, 0.f), 1.f);
            const float Z1 = fminf(fmaxf(px1 + pw1, 0.f), 1.f), W1 = fminf(fmaxf(py1 + ph1, 0.f), 1.f);
            const float pa0 = (Z0 - X0) * (W0 - Y0);
            const float pa1 = (Z1 - X1) * (W1 - Y1);
            const float pw  = fmaxf(fminf(Z0, Z1) - fmaxf(X0, X1), 0.f);
            const float ph  = fmaxf(fminf(W0, W1) - fmaxf(Y0, Y1), 0.f);
            const float pint = pw * ph;
            const float puni = pa0 + pa1 - pint;
            const float iou  = (puni > 0.f) ? (pint / puni) : 0.f;
            kill_local = (iou > NMS_T);
        } else {
            kill_local = (delta > 0.f);
        }
    }
    const bool kill1 = (__ballot(kill_local) != 0ull);

    // ---- packed 64-bit sort key: (ord(score) << 8) | (63-cell)<<2 | cnt ----
    // order: score desc, then cell asc; cnt bits only matter at j==i (excluded)
    const int ib = __float_as_int(s);
    const unsigned uo = (unsigned)ib ^ (unsigned)((ib >> 31) | 0x80000000);
    const unsigned long long key =
        ((unsigned long long)uo << 8) | ((unsigned)(63 - cell) << 2) | (unsigned)cnt;
    const unsigned klo = (unsigned)key;
    const unsigned khi = (unsigned)(key >> 32);

    // rcom = # valid boxes strictly before box 2*cell in sort order
    int acc0 = 0, acc1 = 0, acc2 = 0, acc3 = 0;
    #pragma unroll
    for (int j = 0; j < 49; ++j) {
        const unsigned jlo = (unsigned)__builtin_amdgcn_readlane((int)klo, j);
        const unsigned jhi = (unsigned)__builtin_amdgcn_readlane((int)khi, j);
        const unsigned long long kj = ((unsigned long long)jhi << 32) | jlo;
        const int cj_ = (int)(jlo & 3u);
        const int add = (kj > key) ? cj_ : 0;
        if ((j & 3) == 0) acc0 += add;
        else if ((j & 3) == 1) acc1 += add;
        else if ((j & 3) == 2) acc2 += add;
        else acc3 += add;
    }
    const int rcom = (acc0 + acc1) + (acc2 + acc3);

    // prefix of valid boxes among boxes with index < 2*cell
    const unsigned long long below = (1ull << cell) - 1ull;
    const int prefv = (int)__popcll(V0m & below) + (int)__popcll(V1m & below);

    const int r0 = v0 ? rcom
                      : (V + 2 * cell - prefv);
    const int r1 = v1 ? (rcom + (v0 ? 1 : 0))
                      : (V + 2 * cell + 1 - prefv - (v0 ? 1 : 0));

    // ---- keep flags ----
    const bool k0 = v0 && (s >= SCORE_T);
    const bool k1 = v1 && (s >= SCORE_T) && !(kill1 && cell == 0);

    // ---- scatter outputs: boxes [b,98,4] | scores | labels | keep ----
    if (active) {
        float4* boxes = reinterpret_cast<float4*>(out + (size_t)b * (NBOX * 4));
        const size_t base1 = (size_t)batch * (NBOX * 4);
        const size_t bn    = (size_t)batch * NBOX;
        float* scores = out + base1 +          (size_t)b * NBOX;
        float* labels = out + base1 + bn +     (size_t)b * NBOX;
        float* keepm  = out + base1 + 2 * bn + (size_t)b * NBOX;

        const float4 z = make_float4(0.f, 0.f, 0.f, 0.f);
        boxes[r0]  = k0 ? B0 : z;
        boxes[r1]  = k1 ? B1 : z;
        scores[r0] = k0 ? s : 0.f;
        scores[r1] = k1 ? s : 0.f;
        labels[r0] = k0 ? lab : 0.f;
        labels[r1] = k1 ? lab : 0.f;
        keepm[r0]  = k0 ? 1.f : 0.f;
        keepm[r1]  = k1 ? 1.f : 0.f;
    }
}

extern "C" void kernel_launch(void* const* d_in, const int* in_sizes, int n_in,
                              void* d_out, int out_size, void* d_ws, size_t ws_size,
                              hipStream_t stream) {
    const float* x = (const float*)d_in[0];
    float* out = (float*)d_out;
    const int batch = in_sizes[0] / ROWLEN;   // 8192
    const int grid  = (batch + 1) / 2;        // 2 images (waves) per block
    yolo_post<<<grid, 128, 0, stream>>>(x, out, batch);
}